// Round 2
// 6973.886 us; speedup vs baseline: 1.2963x; 1.2963x over previous
//
#include <hip/hip_runtime.h>
#include <stdint.h>

typedef unsigned short u16;
typedef __attribute__((ext_vector_type(8))) short bf16x8;   // 8 bf16 = 4 VGPRs
typedef __attribute__((ext_vector_type(4))) float f32x4;

#define HDIM 1024
#define BATCH 64
#define SEQ 512
#define CHUNK_T 32
#define NCHUNK (SEQ / CHUNK_T)   // 16
#define WELEM (HDIM * HDIM)      // 1M elements per weight matrix

__device__ __forceinline__ u16 f2bf(float f) {
  union { float f; uint32_t i; } v; v.f = f;
  return (u16)((v.i + 0x7fffu + ((v.i >> 16) & 1u)) >> 16);  // RNE
}

// ---------------------------------------------------------------------------
// fp32 -> bf16 conversion, 4 elements/thread (contiguous)
// ---------------------------------------------------------------------------
__global__ void conv_f2b(const float* __restrict__ s, u16* __restrict__ d, int n4)
{
  int i = blockIdx.x * blockDim.x + threadIdx.x;
  if (i >= n4) return;
  float4 v = ((const float4*)s)[i];
  union { u16 u[4]; uint2 p; } o;
  o.u[0] = f2bf(v.x); o.u[1] = f2bf(v.y); o.u[2] = f2bf(v.z); o.u[3] = f2bf(v.w);
  ((uint2*)d)[i] = o.p;
}

// ---------------------------------------------------------------------------
// Convert one time-chunk of x (fp32 [B,T,H]) into xb (bf16 [R=b*32+tt][H])
// ---------------------------------------------------------------------------
__global__ void conv_x_chunk(const float* __restrict__ x, u16* __restrict__ xb, int chunk)
{
  int i = blockIdx.x * blockDim.x + threadIdx.x;   // 0..524287
  int k4 = i & 255;                                 // 256 float4 per row
  int R  = i >> 8;                                  // 0..2047
  int b  = R >> 5, tt = R & 31;
  float4 v = *(const float4*)(x + (size_t)((b * SEQ) + chunk * CHUNK_T + tt) * HDIM + k4 * 4);
  union { u16 u[4]; uint2 p; } o;
  o.u[0] = f2bf(v.x); o.u[1] = f2bf(v.y); o.u[2] = f2bf(v.z); o.u[3] = f2bf(v.w);
  *(uint2*)(xb + (size_t)R * HDIM + k4 * 4) = o.p;
}

// ---------------------------------------------------------------------------
// Phase 1: G[tt][hc][gate][b][hw] (fp32, one CHUNK_T-chunk) =
//          xb @ W_gate^T + bias_gate  (biases fp32, incl. bxc)
// ---------------------------------------------------------------------------
__launch_bounds__(256, 2)
__global__ void proj_gemm(const u16* __restrict__ xb, const u16* __restrict__ Wxb,
                          const float* __restrict__ bf_, const float* __restrict__ bi_,
                          const float* __restrict__ bo_, const float* __restrict__ bc_,
                          float* __restrict__ G)
{
  const int bm    = blockIdx.x;
  const int by    = blockIdx.y;          // 0..31
  const int gate  = by >> 3;
  const int nbase = (by & 7) * 128;
  const u16* W    = Wxb + (size_t)gate * WELEM;
  const float* bias = (gate == 0) ? bf_ : (gate == 1) ? bi_ : (gate == 2) ? bo_ : bc_;

  __shared__ __align__(16) u16 As[128 * 32];
  __shared__ __align__(16) u16 Bs[128 * 32];

  const int tid  = threadIdx.x;
  const int lane = tid & 63;
  const int wave = tid >> 6;
  const int wm   = wave >> 1, wn = wave & 1;
  const int qrow = lane & 15;
  const int quad = lane >> 4;

  f32x4 acc[4][4];
  #pragma unroll
  for (int a = 0; a < 4; a++)
    #pragma unroll
    for (int b = 0; b < 4; b++) acc[a][b] = (f32x4){0.f, 0.f, 0.f, 0.f};

  for (int k0 = 0; k0 < HDIM; k0 += 32) {
    #pragma unroll
    for (int j = 0; j < 2; j++) {
      int u = j * 256 + tid;             // 0..511
      int r = u >> 2, seg = u & 3;
      *(int4*)(&As[r * 32 + seg * 8]) =
          *(const int4*)(xb + (size_t)(bm * 128 + r) * HDIM + k0 + seg * 8);
      *(int4*)(&Bs[r * 32 + seg * 8]) =
          *(const int4*)(W + (size_t)(nbase + r) * HDIM + k0 + seg * 8);
    }
    __syncthreads();
    bf16x8 afr[4], bfr[4];
    #pragma unroll
    for (int tm = 0; tm < 4; tm++)
      afr[tm] = *(const bf16x8*)(&As[(wm * 64 + tm * 16 + qrow) * 32 + quad * 8]);
    #pragma unroll
    for (int tn = 0; tn < 4; tn++)
      bfr[tn] = *(const bf16x8*)(&Bs[(wn * 64 + tn * 16 + qrow) * 32 + quad * 8]);
    #pragma unroll
    for (int tm = 0; tm < 4; tm++)
      #pragma unroll
      for (int tn = 0; tn < 4; tn++)
        acc[tm][tn] = __builtin_amdgcn_mfma_f32_16x16x32_bf16(afr[tm], bfr[tn], acc[tm][tn], 0, 0, 0);
    __syncthreads();
  }

  #pragma unroll
  for (int tn = 0; tn < 4; tn++) {
    int h  = nbase + wn * 64 + tn * 16 + (lane & 15);
    int hc = h >> 4, hw = h & 15;
    float bv = bias[h];
    #pragma unroll
    for (int tm = 0; tm < 4; tm++) {
      #pragma unroll
      for (int r = 0; r < 4; r++) {
        int R = bm * 128 + wm * 64 + tm * 16 + quad * 4 + r;
        int b = R >> 5, tt = R & 31;
        G[(((size_t)(tt * 64 + hc)) * 4 + gate) * 1024 + b * 16 + hw] = acc[tm][tn][r] + bv;
      }
    }
  }
}

// ---------------------------------------------------------------------------
// Phase 2 (persistent per chunk): 64 blocks (hc), 256 threads (wave = bg).
// ALL THREE recurrent weight slices LDS-resident (96 KB; 1 block/CU).
// G register-prefetched across the grid barrier (double-buffered in VGPRs).
// cbin (remote ct) loads pipelined 2 groups deep via 3-buffer rotation.
// fp32 cell state lives in 4 VGPRs/thread for the whole chunk.
// One agent-scope grid barrier per step (exact r0-proven protocol).
// ---------------------------------------------------------------------------
__launch_bounds__(256, 1)
__global__ void lstm_chunk(const u16* __restrict__ Wcb, const float* __restrict__ G,
                           float* __restrict__ ct, u16* __restrict__ cb0,
                           u16* __restrict__ cb1, float* __restrict__ out,
                           int chunk, int* __restrict__ bar)
{
  const int hc   = blockIdx.x;          // 0..63
  const int tid  = threadIdx.x;
  const int lane = tid & 63;
  const int bg   = tid >> 6;
  const int row  = lane & 15;
  const int quad = lane >> 4;
  const int hw   = row;
  const int h    = hc * 16 + hw;

  __shared__ __align__(16) u16 W3[3 * 16 * 1024];   // 96 KB: gates f,i,o

  // cooperative load, K-major LDS layout: int4 dst idx = s*48 + g*16 + r
  #pragma unroll
  for (int j = 0; j < 24; j++) {
    int v = j * 256 + tid;             // 0..6143
    int g = v >> 11, rem = v & 2047, r = rem >> 7, s = rem & 127;
    ((int4*)W3)[s * 48 + g * 16 + r] =
        *(const int4*)(Wcb + (size_t)g * WELEM + (size_t)(hc * 16 + r) * HDIM + s * 8);
  }

  // cell state registers: (b = bg*16 + quad*4 + r, h)
  float cst[4];
  #pragma unroll
  for (int r = 0; r < 4; r++)
    cst[r] = ct[(size_t)(bg * 16 + quad * 4 + r) * HDIM + h];

  const u16* wlds = W3 + quad * 384 + row * 8;     // + g*128 + kk*1536
  const int boff  = (bg * 16 + quad * 4) * 16 + hw;

  // G prefetch registers, filled for tt = 0 (overlaps LDS fill + syncthreads)
  float gv[16];
  {
    const float* Gt = G + ((size_t)hc) * 4096;
    #pragma unroll
    for (int gg = 0; gg < 4; gg++)
      #pragma unroll
      for (int r = 0; r < 4; r++)
        gv[gg * 4 + r] = Gt[gg * 1024 + boff + r * 16];
  }

  __syncthreads();

  for (int tt = 0; tt < CHUNK_T; tt++) {
    const u16* cbin = (tt & 1) ? cb1 : cb0;
    u16* cbout      = (tt & 1) ? cb0 : cb1;
    const u16* ap   = cbin + (size_t)(bg * 16 + row) * HDIM + quad * 8;

    f32x4 aF = (f32x4){0.f, 0.f, 0.f, 0.f};
    f32x4 aI = aF, aO = aF;

    // --- pipelined K loop: 8 groups of 4 k-steps, prefetch distance 2 ---
    bf16x8 ab[3][4];
    #pragma unroll
    for (int j = 0; j < 4; j++) ab[0][j] = *(const bf16x8*)(ap + j * 32);
    #pragma unroll
    for (int j = 0; j < 4; j++) ab[1][j] = *(const bf16x8*)(ap + 128 + j * 32);

    #pragma unroll
    for (int K0 = 0; K0 < 8; K0++) {
      if (K0 < 6) {
        #pragma unroll
        for (int j = 0; j < 4; j++)
          ab[(K0 + 2) % 3][j] = *(const bf16x8*)(ap + (K0 + 2) * 128 + j * 32);
      }
      #pragma unroll
      for (int j = 0; j < 4; j++) {
        const u16* wb = wlds + (K0 * 4 + j) * 1536;
        bf16x8 a = ab[K0 % 3][j];
        aF = __builtin_amdgcn_mfma_f32_16x16x32_bf16(a, *(const bf16x8*)(wb +   0), aF, 0, 0, 0);
        aI = __builtin_amdgcn_mfma_f32_16x16x32_bf16(a, *(const bf16x8*)(wb + 128), aI, 0, 0, 0);
        aO = __builtin_amdgcn_mfma_f32_16x16x32_bf16(a, *(const bf16x8*)(wb + 256), aO, 0, 0, 0);
      }
    }

    const int t = chunk * CHUNK_T + tt;
    #pragma unroll
    for (int r = 0; r < 4; r++) {
      int b = bg * 16 + quad * 4 + r;
      float zf = gv[0  + r] + aF[r];
      float zi = gv[4  + r] + aI[r];
      float zo = gv[8  + r] + aO[r];
      float zc = gv[12 + r];
      float fg = 1.f / (1.f + __expf(-zf));
      float ig = 1.f / (1.f + __expf(-zi));
      float og = 1.f / (1.f + __expf(-zo));
      float zcl = fminf(fmaxf(zc, -20.f), 20.f);
      float e2  = __expf(2.f * zcl);
      float tzc = (e2 - 1.f) / (e2 + 1.f);
      float cn  = fg * cst[r] + ig * tzc;
      cst[r] = cn;
      float cc  = fminf(fmaxf(cn, -20.f), 20.f);
      float e2c = __expf(2.f * cc);
      float th  = (e2c - 1.f) / (e2c + 1.f);
      float hv  = og * th;
      cbout[(size_t)b * HDIM + h] = f2bf(cn);
      out[((size_t)b * SEQ + t) * HDIM + h] = hv;
      if (t == SEQ - 1) out[(size_t)BATCH * SEQ * HDIM + (size_t)b * HDIM + h] = hv;
    }

    // prefetch G for step tt+1 BEFORE the barrier: loads drain (vmcnt) during
    // the fence/spin, so their HBM/L3 latency is fully hidden.
    {
      const int tn = (tt < CHUNK_T - 1) ? tt + 1 : tt;
      const float* Gt = G + ((size_t)(tn * 64 + hc)) * 4096;
      #pragma unroll
      for (int gg = 0; gg < 4; gg++)
        #pragma unroll
        for (int r = 0; r < 4; r++)
          gv[gg * 4 + r] = Gt[gg * 1024 + boff + r * 16];
    }

    // grid barrier (agent scope): separates step-t reads from step-t+1 writes
    __syncthreads();
    if (tid == 0) {
      __threadfence();
      __hip_atomic_fetch_add(bar, 1, __ATOMIC_RELEASE, __HIP_MEMORY_SCOPE_AGENT);
      while (__hip_atomic_load(bar, __ATOMIC_ACQUIRE, __HIP_MEMORY_SCOPE_AGENT) < 64 * (tt + 1)) {}
      __threadfence();
    }
    __syncthreads();
  }

  #pragma unroll
  for (int r = 0; r < 4; r++)
    ct[(size_t)(bg * 16 + quad * 4 + r) * HDIM + h] = cst[r];
}

__global__ void init_ct(const float* __restrict__ c0, float* __restrict__ ct,
                        u16* __restrict__ ctb)
{
  int idx = blockIdx.x * blockDim.x + threadIdx.x;   // 0..65535
  int hh = idx & (HDIM - 1);
  float v = c0[hh];                                   // broadcast [1,H] -> [B,H]
  ct[idx] = v;
  ctb[idx] = f2bf(v);
}

extern "C" void kernel_launch(void* const* d_in, const int* in_sizes, int n_in,
                              void* d_out, int out_size, void* d_ws, size_t ws_size,
                              hipStream_t stream)
{
  (void)in_sizes; (void)n_in; (void)out_size; (void)ws_size;
  const float* x   = (const float*)d_in[0];
  const float* Wxf = (const float*)d_in[1];
  const float* Wcf = (const float*)d_in[2];
  const float* bcf = (const float*)d_in[3];
  const float* Wxi = (const float*)d_in[4];
  const float* Wci = (const float*)d_in[5];
  const float* bci = (const float*)d_in[6];
  const float* Wxo = (const float*)d_in[7];
  const float* Wco = (const float*)d_in[8];
  const float* bco = (const float*)d_in[9];
  const float* Wxc = (const float*)d_in[10];
  const float* bxc = (const float*)d_in[11];
  const float* c0  = (const float*)d_in[12];
  float* out = (float*)d_out;

  char* ws = (char*)d_ws;
  size_t off = 0;
  float* G   = (float*)(ws + off); off += (size_t)CHUNK_T * 64 * 4 * 64 * 16 * 4; // 32 MB
  u16* xb    = (u16*)(ws + off);   off += (size_t)CHUNK_T * BATCH * HDIM * 2;     // 4 MB
  u16* Wxb   = (u16*)(ws + off);   off += (size_t)4 * WELEM * 2;                  // 8 MB
  u16* Wcb   = (u16*)(ws + off);   off += (size_t)3 * WELEM * 2;                  // 6 MB
  float* ct  = (float*)(ws + off); off += (size_t)BATCH * HDIM * 4;
  u16* cb0   = (u16*)(ws + off);   off += (size_t)BATCH * HDIM * 2;
  u16* cb1   = (u16*)(ws + off);   off += (size_t)BATCH * HDIM * 2;
  int* bar   = (int*)(ws + off);   off += 64 * sizeof(int);

  hipMemsetAsync(bar, 0, 64 * sizeof(int), stream);

  const int n4w = WELEM / 4, cbs = 256, cgs = n4w / cbs;
  conv_f2b<<<cgs, cbs, 0, stream>>>(Wxf, Wxb + 0 * (size_t)WELEM, n4w);
  conv_f2b<<<cgs, cbs, 0, stream>>>(Wxi, Wxb + 1 * (size_t)WELEM, n4w);
  conv_f2b<<<cgs, cbs, 0, stream>>>(Wxo, Wxb + 2 * (size_t)WELEM, n4w);
  conv_f2b<<<cgs, cbs, 0, stream>>>(Wxc, Wxb + 3 * (size_t)WELEM, n4w);
  conv_f2b<<<cgs, cbs, 0, stream>>>(Wcf, Wcb + 0 * (size_t)WELEM, n4w);
  conv_f2b<<<cgs, cbs, 0, stream>>>(Wci, Wcb + 1 * (size_t)WELEM, n4w);
  conv_f2b<<<cgs, cbs, 0, stream>>>(Wco, Wcb + 2 * (size_t)WELEM, n4w);

  init_ct<<<64, 1024, 0, stream>>>(c0, ct, cb0);

  for (int chunk = 0; chunk < NCHUNK; chunk++) {
    conv_x_chunk<<<2048, 256, 0, stream>>>(x, xb, chunk);
    proj_gemm<<<dim3(16, 32), 256, 0, stream>>>(xb, Wxb, bcf, bci, bco, bxc, G);
    lstm_chunk<<<64, 256, 0, stream>>>(Wcb, G, ct, cb0, cb1, out, chunk, bar + chunk);
  }
}

// Round 3
// 5382.082 us; speedup vs baseline: 1.6797x; 1.2958x over previous
//
#include <hip/hip_runtime.h>
#include <stdint.h>

typedef unsigned short u16;
typedef __attribute__((ext_vector_type(8))) short bf16x8;   // 8 bf16 = 4 VGPRs
typedef __attribute__((ext_vector_type(4))) float f32x4;

#define HDIM 1024
#define BATCH 64
#define SEQ 512
#define CHUNK_T 32
#define NCHUNK (SEQ / CHUNK_T)   // 16
#define WELEM (HDIM * HDIM)      // 1M elements per weight matrix
#define FLAG_STRIDE 32           // 128 B between per-block flags

__device__ __forceinline__ u16 f2bf(float f) {
  union { float f; uint32_t i; } v; v.f = f;
  return (u16)((v.i + 0x7fffu + ((v.i >> 16) & 1u)) >> 16);  // RNE
}

// Coherent (agent-scope, L1/L2-bypassing) 16B load: two relaxed 8B atomic loads.
__device__ __forceinline__ bf16x8 ldcoh(const u16* p) {
  union { bf16x8 v; unsigned long long q[2]; } u;
  u.q[0] = __hip_atomic_load((const unsigned long long*)p,
                             __ATOMIC_RELAXED, __HIP_MEMORY_SCOPE_AGENT);
  u.q[1] = __hip_atomic_load((const unsigned long long*)(p + 4),
                             __ATOMIC_RELAXED, __HIP_MEMORY_SCOPE_AGENT);
  return u.v;
}

// Coherent 2B store (write-through to coherence point).
__device__ __forceinline__ void stcoh16(u16* p, unsigned v) {
  asm volatile("global_store_short %0, %1, off sc0 sc1"
               :: "v"((unsigned long long)(uintptr_t)p), "v"(v) : "memory");
}

// ---------------------------------------------------------------------------
// fp32 -> bf16 conversion, 4 elements/thread (contiguous)
// ---------------------------------------------------------------------------
__global__ void conv_f2b(const float* __restrict__ s, u16* __restrict__ d, int n4)
{
  int i = blockIdx.x * blockDim.x + threadIdx.x;
  if (i >= n4) return;
  float4 v = ((const float4*)s)[i];
  union { u16 u[4]; uint2 p; } o;
  o.u[0] = f2bf(v.x); o.u[1] = f2bf(v.y); o.u[2] = f2bf(v.z); o.u[3] = f2bf(v.w);
  ((uint2*)d)[i] = o.p;
}

// ---------------------------------------------------------------------------
// Convert one time-chunk of x (fp32 [B,T,H]) into xb (bf16 [R=b*32+tt][H])
// ---------------------------------------------------------------------------
__global__ void conv_x_chunk(const float* __restrict__ x, u16* __restrict__ xb, int chunk)
{
  int i = blockIdx.x * blockDim.x + threadIdx.x;   // 0..524287
  int k4 = i & 255;                                 // 256 float4 per row
  int R  = i >> 8;                                  // 0..2047
  int b  = R >> 5, tt = R & 31;
  float4 v = *(const float4*)(x + (size_t)((b * SEQ) + chunk * CHUNK_T + tt) * HDIM + k4 * 4);
  union { u16 u[4]; uint2 p; } o;
  o.u[0] = f2bf(v.x); o.u[1] = f2bf(v.y); o.u[2] = f2bf(v.z); o.u[3] = f2bf(v.w);
  *(uint2*)(xb + (size_t)R * HDIM + k4 * 4) = o.p;
}

// ---------------------------------------------------------------------------
// Phase 1: G[tt][hc][gate][b][hw] (fp32, one CHUNK_T-chunk) =
//          xb @ W_gate^T + bias_gate  (biases fp32, incl. bxc)
// ---------------------------------------------------------------------------
__launch_bounds__(256, 2)
__global__ void proj_gemm(const u16* __restrict__ xb, const u16* __restrict__ Wxb,
                          const float* __restrict__ bf_, const float* __restrict__ bi_,
                          const float* __restrict__ bo_, const float* __restrict__ bc_,
                          float* __restrict__ G)
{
  const int bm    = blockIdx.x;
  const int by    = blockIdx.y;          // 0..31
  const int gate  = by >> 3;
  const int nbase = (by & 7) * 128;
  const u16* W    = Wxb + (size_t)gate * WELEM;
  const float* bias = (gate == 0) ? bf_ : (gate == 1) ? bi_ : (gate == 2) ? bo_ : bc_;

  __shared__ __align__(16) u16 As[128 * 32];
  __shared__ __align__(16) u16 Bs[128 * 32];

  const int tid  = threadIdx.x;
  const int lane = tid & 63;
  const int wave = tid >> 6;
  const int wm   = wave >> 1, wn = wave & 1;
  const int qrow = lane & 15;
  const int quad = lane >> 4;

  f32x4 acc[4][4];
  #pragma unroll
  for (int a = 0; a < 4; a++)
    #pragma unroll
    for (int b = 0; b < 4; b++) acc[a][b] = (f32x4){0.f, 0.f, 0.f, 0.f};

  for (int k0 = 0; k0 < HDIM; k0 += 32) {
    #pragma unroll
    for (int j = 0; j < 2; j++) {
      int u = j * 256 + tid;             // 0..511
      int r = u >> 2, seg = u & 3;
      *(int4*)(&As[r * 32 + seg * 8]) =
          *(const int4*)(xb + (size_t)(bm * 128 + r) * HDIM + k0 + seg * 8);
      *(int4*)(&Bs[r * 32 + seg * 8]) =
          *(const int4*)(W + (size_t)(nbase + r) * HDIM + k0 + seg * 8);
    }
    __syncthreads();
    bf16x8 afr[4], bfr[4];
    #pragma unroll
    for (int tm = 0; tm < 4; tm++)
      afr[tm] = *(const bf16x8*)(&As[(wm * 64 + tm * 16 + qrow) * 32 + quad * 8]);
    #pragma unroll
    for (int tn = 0; tn < 4; tn++)
      bfr[tn] = *(const bf16x8*)(&Bs[(wn * 64 + tn * 16 + qrow) * 32 + quad * 8]);
    #pragma unroll
    for (int tm = 0; tm < 4; tm++)
      #pragma unroll
      for (int tn = 0; tn < 4; tn++)
        acc[tm][tn] = __builtin_amdgcn_mfma_f32_16x16x32_bf16(afr[tm], bfr[tn], acc[tm][tn], 0, 0, 0);
    __syncthreads();
  }

  #pragma unroll
  for (int tn = 0; tn < 4; tn++) {
    int h  = nbase + wn * 64 + tn * 16 + (lane & 15);
    int hc = h >> 4, hw = h & 15;
    float bv = bias[h];
    #pragma unroll
    for (int tm = 0; tm < 4; tm++) {
      #pragma unroll
      for (int r = 0; r < 4; r++) {
        int R = bm * 128 + wm * 64 + tm * 16 + quad * 4 + r;
        int b = R >> 5, tt = R & 31;
        G[(((size_t)(tt * 64 + hc)) * 4 + gate) * 1024 + b * 16 + hw] = acc[tm][tn][r] + bv;
      }
    }
  }
}

// ---------------------------------------------------------------------------
// Phase 2 (persistent per chunk): 64 blocks (hc), 256 threads (wave = bg).
// ALL THREE recurrent weight slices LDS-resident (96 KB; 1 block/CU).
// Fence-free step protocol: cb state exchanged via agent-coherent (sc0 sc1)
// loads/stores that live at L3; arrival = one relaxed flag store per block on
// its own 128B line; departure = 64-lane parallel flag poll. No threadfence,
// no L2 writeback/invalidate, no contended atomic RMW.
// G register-prefetched between signal and poll (latency hidden under poll).
// ---------------------------------------------------------------------------
__launch_bounds__(256, 1)
__global__ void lstm_chunk(const u16* __restrict__ Wcb, const float* __restrict__ G,
                           float* __restrict__ ct, u16* __restrict__ cb0,
                           u16* __restrict__ cb1, float* __restrict__ out,
                           int chunk, unsigned* __restrict__ flags)
{
  const int hc   = blockIdx.x;          // 0..63
  const int tid  = threadIdx.x;
  const int lane = tid & 63;
  const int bg   = tid >> 6;
  const int row  = lane & 15;
  const int quad = lane >> 4;
  const int hw   = row;
  const int h    = hc * 16 + hw;
  const int gbase = chunk * CHUNK_T;

  __shared__ __align__(16) u16 W3[3 * 16 * 1024];   // 96 KB: gates f,i,o

  // cooperative load, K-major LDS layout: int4 dst idx = s*48 + g*16 + r
  #pragma unroll
  for (int j = 0; j < 24; j++) {
    int v = j * 256 + tid;             // 0..6143
    int g = v >> 11, rem = v & 2047, r = rem >> 7, s = rem & 127;
    ((int4*)W3)[s * 48 + g * 16 + r] =
        *(const int4*)(Wcb + (size_t)g * WELEM + (size_t)(hc * 16 + r) * HDIM + s * 8);
  }

  // cell state registers: (b = bg*16 + quad*4 + r, h)
  float cst[4];
  #pragma unroll
  for (int r = 0; r < 4; r++)
    cst[r] = ct[(size_t)(bg * 16 + quad * 4 + r) * HDIM + h];

  const u16* wlds = W3 + quad * 384 + row * 8;     // + g*128 + kk*1536
  const int boff  = (bg * 16 + quad * 4) * 16 + hw;

  // G prefetch registers, filled for tt = 0 (overlaps LDS fill + syncthreads)
  float gv[16];
  {
    const float* Gt = G + ((size_t)hc) * 4096;
    #pragma unroll
    for (int gg = 0; gg < 4; gg++)
      #pragma unroll
      for (int r = 0; r < 4; r++)
        gv[gg * 4 + r] = Gt[gg * 1024 + boff + r * 16];
  }

  __syncthreads();

  for (int tt = 0; tt < CHUNK_T; tt++) {
    const u16* cbin = (tt & 1) ? cb1 : cb0;
    u16* cbout      = (tt & 1) ? cb0 : cb1;
    const u16* ap   = cbin + (size_t)(bg * 16 + row) * HDIM + quad * 8;

    f32x4 aF = (f32x4){0.f, 0.f, 0.f, 0.f};
    f32x4 aI = aF, aO = aF;

    // --- pipelined K loop: 8 groups of 4 k-steps, prefetch distance 2 ---
    bf16x8 ab[3][4];
    #pragma unroll
    for (int j = 0; j < 4; j++) ab[0][j] = ldcoh(ap + j * 32);
    #pragma unroll
    for (int j = 0; j < 4; j++) ab[1][j] = ldcoh(ap + 128 + j * 32);

    #pragma unroll
    for (int K0 = 0; K0 < 8; K0++) {
      if (K0 < 6) {
        #pragma unroll
        for (int j = 0; j < 4; j++)
          ab[(K0 + 2) % 3][j] = ldcoh(ap + (K0 + 2) * 128 + j * 32);
      }
      #pragma unroll
      for (int j = 0; j < 4; j++) {
        const u16* wb = wlds + (K0 * 4 + j) * 1536;
        bf16x8 a = ab[K0 % 3][j];
        aF = __builtin_amdgcn_mfma_f32_16x16x32_bf16(a, *(const bf16x8*)(wb +   0), aF, 0, 0, 0);
        aI = __builtin_amdgcn_mfma_f32_16x16x32_bf16(a, *(const bf16x8*)(wb + 128), aI, 0, 0, 0);
        aO = __builtin_amdgcn_mfma_f32_16x16x32_bf16(a, *(const bf16x8*)(wb + 256), aO, 0, 0, 0);
      }
    }

    const int t = gbase + tt;
    #pragma unroll
    for (int r = 0; r < 4; r++) {
      int b = bg * 16 + quad * 4 + r;
      float zf = gv[0  + r] + aF[r];
      float zi = gv[4  + r] + aI[r];
      float zo = gv[8  + r] + aO[r];
      float zc = gv[12 + r];
      float fg = 1.f / (1.f + __expf(-zf));
      float ig = 1.f / (1.f + __expf(-zi));
      float og = 1.f / (1.f + __expf(-zo));
      float zcl = fminf(fmaxf(zc, -20.f), 20.f);
      float e2  = __expf(2.f * zcl);
      float tzc = (e2 - 1.f) / (e2 + 1.f);
      float cn  = fg * cst[r] + ig * tzc;
      cst[r] = cn;
      float cc  = fminf(fmaxf(cn, -20.f), 20.f);
      float e2c = __expf(2.f * cc);
      float th  = (e2c - 1.f) / (e2c + 1.f);
      float hv  = og * th;
      stcoh16(cbout + (size_t)b * HDIM + h, (unsigned)f2bf(cn));
      out[((size_t)b * SEQ + t) * HDIM + h] = hv;
      if (t == SEQ - 1) out[(size_t)BATCH * SEQ * HDIM + (size_t)b * HDIM + h] = hv;
    }

    // --- fence-free grid barrier ---
    // syncthreads: every wave of this block drains vmcnt (coherent stores now
    // globally visible at L3) before the flag is published.
    __syncthreads();
    if (tid == 0)
      __hip_atomic_store(&flags[hc * FLAG_STRIDE], (unsigned)(gbase + tt + 1),
                         __ATOMIC_RELAXED, __HIP_MEMORY_SCOPE_AGENT);

    // G prefetch for step tt+1, issued before the poll so its HBM/L3 latency
    // hides under the flag spin.
    {
      const int tn = (tt < CHUNK_T - 1) ? tt + 1 : tt;
      const float* Gt = G + ((size_t)(tn * 64 + hc)) * 4096;
      #pragma unroll
      for (int gg = 0; gg < 4; gg++)
        #pragma unroll
        for (int r = 0; r < 4; r++)
          gv[gg * 4 + r] = Gt[gg * 1024 + boff + r * 16];
    }

    // departure: each wave's 64 lanes watch the 64 per-block flags in parallel.
    {
      const unsigned tgt = (unsigned)(gbase + tt + 1);
      const unsigned* fp = flags + lane * FLAG_STRIDE;
      while (!__all((int)(__hip_atomic_load(fp, __ATOMIC_RELAXED,
                                            __HIP_MEMORY_SCOPE_AGENT) >= tgt))) {}
      asm volatile("" ::: "memory");   // compiler fence: no hoisting of cbin reads
    }
  }

  #pragma unroll
  for (int r = 0; r < 4; r++)
    ct[(size_t)(bg * 16 + quad * 4 + r) * HDIM + h] = cst[r];
}

__global__ void init_ct(const float* __restrict__ c0, float* __restrict__ ct,
                        u16* __restrict__ ctb)
{
  int idx = blockIdx.x * blockDim.x + threadIdx.x;   // 0..65535
  int hh = idx & (HDIM - 1);
  float v = c0[hh];                                   // broadcast [1,H] -> [B,H]
  ct[idx] = v;
  ctb[idx] = f2bf(v);
}

extern "C" void kernel_launch(void* const* d_in, const int* in_sizes, int n_in,
                              void* d_out, int out_size, void* d_ws, size_t ws_size,
                              hipStream_t stream)
{
  (void)in_sizes; (void)n_in; (void)out_size; (void)ws_size;
  const float* x   = (const float*)d_in[0];
  const float* Wxf = (const float*)d_in[1];
  const float* Wcf = (const float*)d_in[2];
  const float* bcf = (const float*)d_in[3];
  const float* Wxi = (const float*)d_in[4];
  const float* Wci = (const float*)d_in[5];
  const float* bci = (const float*)d_in[6];
  const float* Wxo = (const float*)d_in[7];
  const float* Wco = (const float*)d_in[8];
  const float* bco = (const float*)d_in[9];
  const float* Wxc = (const float*)d_in[10];
  const float* bxc = (const float*)d_in[11];
  const float* c0  = (const float*)d_in[12];
  float* out = (float*)d_out;

  char* ws = (char*)d_ws;
  size_t off = 0;
  float* G   = (float*)(ws + off); off += (size_t)CHUNK_T * 64 * 4 * 64 * 16 * 4; // 32 MB
  u16* xb    = (u16*)(ws + off);   off += (size_t)CHUNK_T * BATCH * HDIM * 2;     // 4 MB
  u16* Wxb   = (u16*)(ws + off);   off += (size_t)4 * WELEM * 2;                  // 8 MB
  u16* Wcb   = (u16*)(ws + off);   off += (size_t)3 * WELEM * 2;                  // 6 MB
  float* ct  = (float*)(ws + off); off += (size_t)BATCH * HDIM * 4;
  u16* cb0   = (u16*)(ws + off);   off += (size_t)BATCH * HDIM * 2;
  u16* cb1   = (u16*)(ws + off);   off += (size_t)BATCH * HDIM * 2;
  unsigned* flags = (unsigned*)(ws + off); off += (size_t)64 * FLAG_STRIDE * 4;   // 8 KB

  hipMemsetAsync(flags, 0, (size_t)64 * FLAG_STRIDE * 4, stream);

  const int n4w = WELEM / 4, cbs = 256, cgs = n4w / cbs;
  conv_f2b<<<cgs, cbs, 0, stream>>>(Wxf, Wxb + 0 * (size_t)WELEM, n4w);
  conv_f2b<<<cgs, cbs, 0, stream>>>(Wxi, Wxb + 1 * (size_t)WELEM, n4w);
  conv_f2b<<<cgs, cbs, 0, stream>>>(Wxo, Wxb + 2 * (size_t)WELEM, n4w);
  conv_f2b<<<cgs, cbs, 0, stream>>>(Wxc, Wxb + 3 * (size_t)WELEM, n4w);
  conv_f2b<<<cgs, cbs, 0, stream>>>(Wcf, Wcb + 0 * (size_t)WELEM, n4w);
  conv_f2b<<<cgs, cbs, 0, stream>>>(Wci, Wcb + 1 * (size_t)WELEM, n4w);
  conv_f2b<<<cgs, cbs, 0, stream>>>(Wco, Wcb + 2 * (size_t)WELEM, n4w);

  init_ct<<<64, 1024, 0, stream>>>(c0, ct, cb0);

  for (int chunk = 0; chunk < NCHUNK; chunk++) {
    conv_x_chunk<<<2048, 256, 0, stream>>>(x, xb, chunk);
    proj_gemm<<<dim3(16, 32), 256, 0, stream>>>(xb, Wxb, bcf, bci, bco, bxc, G);
    lstm_chunk<<<64, 256, 0, stream>>>(Wcb, G, ct, cb0, cb1, out, chunk, flags);
  }
}